// Round 1
// baseline (358.541 us; speedup 1.0000x reference)
//
#include <hip/hip_runtime.h>
#include <hip/hip_bf16.h>
#include <stdint.h>

#define N_ROWS 8192
#define DIM    1024
#define INV_T  14.2857142857142857f   // 1/0.07

#define BM 128
#define BN 128
#define BK 64
#define CT 4    // col-tiles per block

typedef __bf16 bf16x8 __attribute__((ext_vector_type(8)));
typedef float  f32x4  __attribute__((ext_vector_type(4)));

__device__ __forceinline__ unsigned short f2bf(float x) {
    __hip_bfloat16 h = __float2bfloat16(x);
    return *reinterpret_cast<unsigned short*>(&h);
}

// ---------------- kernel 1: row-normalize f32 -> bf16 ----------------
__global__ __launch_bounds__(256) void norm_kernel(
    const float* __restrict__ V, unsigned short* __restrict__ A)
{
    const int row  = blockIdx.x;
    const int tid  = threadIdx.x;
    const int lane = tid & 63, wid = tid >> 6;

    const float4* vp = (const float4*)(V + (size_t)row * DIM);
    float4 v = vp[tid];                       // 4 floats / thread, 256 thr = 1024
    float ss = v.x*v.x + v.y*v.y + v.z*v.z + v.w*v.w;
    #pragma unroll
    for (int off = 32; off > 0; off >>= 1) ss += __shfl_down(ss, off, 64);

    __shared__ float wsum[4];
    if (lane == 0) wsum[wid] = ss;
    __syncthreads();
    const float inv = 1.0f / sqrtf(wsum[0] + wsum[1] + wsum[2] + wsum[3]);

    ushort4 o;
    o.x = f2bf(v.x * inv);
    o.y = f2bf(v.y * inv);
    o.z = f2bf(v.z * inv);
    o.w = f2bf(v.w * inv);
    *(ushort4*)(A + (size_t)row * DIM + tid * 4) = o;
}

// ---------------- kernel 2: fused sim GEMM + epilogue reduce ----------------
// grid: (64 row-tiles, 16 col-slices), block: 256 threads (4 waves, 2x2 of 64x64)
__global__ __launch_bounds__(256) void sim_kernel(
    const unsigned short* __restrict__ A, const int* __restrict__ labels,
    float* __restrict__ gsum, float* __restrict__ gpos, float* __restrict__ gcnt)
{
    __shared__ __align__(16) unsigned short As[BM * BK];
    __shared__ __align__(16) unsigned short Bs[BN * BK];

    const int tid  = threadIdx.x;
    const int lane = tid & 63;
    const int wid  = tid >> 6;
    const int wr   = wid >> 1;      // 0..1 wave row
    const int wc   = wid & 1;       // 0..1 wave col

    const int rt    = blockIdx.x;
    const int rbase = rt * BM;

    // lane's base row for accumulator element (m, r): rowq + m*16 + r
    const int rowq = rbase + wr * 64 + ((lane >> 4) << 2);

    int labr[16];
    #pragma unroll
    for (int m = 0; m < 4; ++m)
        #pragma unroll
        for (int r = 0; r < 4; ++r)
            labr[m * 4 + r] = labels[rowq + m * 16 + r];

    float sum_p[16], pos_p[16], cnt_p[16];
    #pragma unroll
    for (int i = 0; i < 16; ++i) { sum_p[i] = 0.f; pos_p[i] = 0.f; cnt_p[i] = 0.f; }

    for (int ctl = 0; ctl < CT; ++ctl) {
        const int ctg   = blockIdx.y * CT + ctl;
        const int cbase = ctg * BN;

        f32x4 acc[4][4];
        #pragma unroll
        for (int m = 0; m < 4; ++m)
            #pragma unroll
            for (int n = 0; n < 4; ++n)
                acc[m][n] = (f32x4){0.f, 0.f, 0.f, 0.f};

        for (int kt = 0; kt < DIM / BK; ++kt) {
            const int kbase = kt * BK;
            // stage A,B tiles: thread covers 16B chunk c = i*256+tid; row=c>>3, kc=c&7
            #pragma unroll
            for (int i = 0; i < 4; ++i) {
                const int c    = i * 256 + tid;
                const int rowc = c >> 3;
                const int kc   = c & 7;
                const unsigned short* gA = A + (size_t)(rbase + rowc) * DIM + kbase + kc * 8;
                const unsigned short* gB = A + (size_t)(cbase + rowc) * DIM + kbase + kc * 8;
                const int ldsOff = i * 4096 + wid * 1024;   // bytes; +lane*16 by HW
                __builtin_amdgcn_global_load_lds(
                    (const __attribute__((address_space(1))) void*)gA,
                    (__attribute__((address_space(3))) void*)((char*)As + ldsOff),
                    16, 0, 0);
                __builtin_amdgcn_global_load_lds(
                    (const __attribute__((address_space(1))) void*)gB,
                    (__attribute__((address_space(3))) void*)((char*)Bs + ldsOff),
                    16, 0, 0);
            }
            __syncthreads();

            #pragma unroll
            for (int ks = 0; ks < 2; ++ks) {
                const int kofs = ks * 32 + ((lane >> 4) << 3);
                bf16x8 af[4], bfr[4];
                #pragma unroll
                for (int m = 0; m < 4; ++m) {
                    const int rowa = wr * 64 + m * 16 + (lane & 15);
                    af[m] = *(const bf16x8*)&As[rowa * BK + kofs];
                }
                #pragma unroll
                for (int n = 0; n < 4; ++n) {
                    const int rowb = wc * 64 + n * 16 + (lane & 15);
                    bfr[n] = *(const bf16x8*)&Bs[rowb * BK + kofs];
                }
                #pragma unroll
                for (int m = 0; m < 4; ++m)
                    #pragma unroll
                    for (int n = 0; n < 4; ++n)
                        acc[m][n] = __builtin_amdgcn_mfma_f32_16x16x32_bf16(
                            af[m], bfr[n], acc[m][n], 0, 0, 0);
            }
            __syncthreads();
        }

        // epilogue for this col tile
        const int col0 = cbase + wc * 64 + (lane & 15);
        int labc[4];
        #pragma unroll
        for (int n = 0; n < 4; ++n) labc[n] = labels[col0 + n * 16];
        const bool diagTile = (ctg == rt);

        #pragma unroll
        for (int m = 0; m < 4; ++m) {
            #pragma unroll
            for (int n = 0; n < 4; ++n) {
                const int gcol = col0 + n * 16;
                #pragma unroll
                for (int r = 0; r < 4; ++r) {
                    const float s    = acc[m][n][r] * INV_T;
                    const int   grow = rowq + m * 16 + r;
                    const bool  diag = diagTile && (grow == gcol);
                    const float e    = diag ? 0.f : __expf(s);
                    const bool  same = (labr[m * 4 + r] == labc[n]) && !diag;
                    sum_p[m * 4 + r] += e;
                    if (same) { pos_p[m * 4 + r] += s; cnt_p[m * 4 + r] += 1.f; }
                }
            }
        }
    }

    // reduce across the 16 lanes sharing each row, then atomics
    #pragma unroll
    for (int i = 0; i < 16; ++i) {
        float se = sum_p[i], pp = pos_p[i], cc = cnt_p[i];
        #pragma unroll
        for (int off = 1; off < 16; off <<= 1) {
            se += __shfl_xor(se, off, 16);
            pp += __shfl_xor(pp, off, 16);
            cc += __shfl_xor(cc, off, 16);
        }
        if ((lane & 15) == 0) {
            const int row = rowq + (i >> 2) * 16 + (i & 3);
            atomicAdd(&gsum[row], se);
            atomicAdd(&gpos[row], pp);
            atomicAdd(&gcnt[row], cc);
        }
    }
}

// ---------------- kernel 3: finalize ----------------
__global__ __launch_bounds__(1024) void finalize_kernel(
    const float* __restrict__ gsum, const float* __restrict__ gpos,
    const float* __restrict__ gcnt, float* __restrict__ out)
{
    const int tid = threadIdx.x;
    float acc = 0.f;
    for (int r = tid; r < N_ROWS; r += 1024) {
        const float c = gcnt[r];
        if (c > 0.f) acc += logf(gsum[r]) - gpos[r] / c;
    }
    #pragma unroll
    for (int off = 32; off > 0; off >>= 1) acc += __shfl_down(acc, off, 64);
    __shared__ float ws[16];
    const int lane = tid & 63, wid = tid >> 6;
    if (lane == 0) ws[wid] = acc;
    __syncthreads();
    if (tid == 0) {
        float t = 0.f;
        #pragma unroll
        for (int i = 0; i < 16; ++i) t += ws[i];
        out[0] = t;
    }
}

extern "C" void kernel_launch(void* const* d_in, const int* in_sizes, int n_in,
                              void* d_out, int out_size, void* d_ws, size_t ws_size,
                              hipStream_t stream) {
    const float* V      = (const float*)d_in[0];
    const int*   labels = (const int*)d_in[1];
    float*       out    = (float*)d_out;

    unsigned short* Abf = (unsigned short*)d_ws;                      // 16 MB
    float* gsum = (float*)((char*)d_ws + (size_t)N_ROWS * DIM * 2);
    float* gpos = gsum + N_ROWS;
    float* gcnt = gpos + N_ROWS;

    hipMemsetAsync(gsum, 0, 3 * N_ROWS * sizeof(float), stream);
    norm_kernel<<<N_ROWS, 256, 0, stream>>>(V, Abf);
    dim3 grid(N_ROWS / BM, (N_ROWS / BN) / CT);
    sim_kernel<<<grid, 256, 0, stream>>>(Abf, labels, gsum, gpos, gcnt);
    finalize_kernel<<<1, 1024, 0, stream>>>(gsum, gpos, gcnt, out);
}

// Round 2
// 313.871 us; speedup vs baseline: 1.1423x; 1.1423x over previous
//
#include <hip/hip_runtime.h>
#include <hip/hip_bf16.h>
#include <stdint.h>

#define N_ROWS 8192
#define DIM    1024
#define INV_T  14.2857142857142857f   // 1/0.07

#define BM 128
#define BK 64

typedef __bf16 bf16x8 __attribute__((ext_vector_type(8)));
typedef float  f32x4  __attribute__((ext_vector_type(4)));

__device__ __forceinline__ unsigned short f2bf(float x) {
    __hip_bfloat16 h = __float2bfloat16(x);
    return *reinterpret_cast<unsigned short*>(&h);
}

// ---------------- kernel 1: row-normalize f32 -> bf16 ----------------
__global__ __launch_bounds__(256) void norm_kernel(
    const float* __restrict__ V, unsigned short* __restrict__ A)
{
    const int row  = blockIdx.x;
    const int tid  = threadIdx.x;
    const int lane = tid & 63, wid = tid >> 6;

    const float4* vp = (const float4*)(V + (size_t)row * DIM);
    float4 v = vp[tid];                       // 4 floats / thread, 256 thr = 1024
    float ss = v.x*v.x + v.y*v.y + v.z*v.z + v.w*v.w;
    #pragma unroll
    for (int off = 32; off > 0; off >>= 1) ss += __shfl_down(ss, off, 64);

    __shared__ float wsum[4];
    if (lane == 0) wsum[wid] = ss;
    __syncthreads();
    const float inv = 1.0f / sqrtf(wsum[0] + wsum[1] + wsum[2] + wsum[3]);

    ushort4 o;
    o.x = f2bf(v.x * inv);
    o.y = f2bf(v.y * inv);
    o.z = f2bf(v.z * inv);
    o.w = f2bf(v.w * inv);
    *(ushort4*)(A + (size_t)row * DIM + tid * 4) = o;
}

// ---------------- kernel 2: fused symmetric sim GEMM + epilogue ----------------
// grid (64,64); block (rt=x, ct=y) active iff ct >= rt. 256 thr = 4 waves (2x2 of 64x64).
// Off-diagonal tiles contribute to BOTH row-side (rows of rt-tile) and col-side
// (rows of ct-tile). Diagonal tiles are full squares -> row-side only.
__global__ __launch_bounds__(256) void sim_kernel(
    const unsigned short* __restrict__ A, const int* __restrict__ labels,
    float* __restrict__ gsum, float* __restrict__ gpos, float* __restrict__ gcnt)
{
    __shared__ __align__(16) unsigned short As[2][BM * BK];
    __shared__ __align__(16) unsigned short Bs[2][BM * BK];

    const int rt = blockIdx.x, ct = blockIdx.y;
    if (ct < rt) return;
    const bool isDiag = (ct == rt);

    const int tid  = threadIdx.x;
    const int lane = tid & 63;
    const int wid  = tid >> 6;
    const int wr   = wid >> 1;      // wave row 0..1
    const int wc   = wid & 1;       // wave col 0..1

    const int rbase = rt * BM;
    const int cbase = ct * BM;

    // lane's base row for accumulator element (m, r): rowq + m*16 + r
    const int rowq = rbase + wr * 64 + ((lane >> 4) << 2);
    const int col0 = cbase + wc * 64 + (lane & 15);

    int labr[16];
    #pragma unroll
    for (int m = 0; m < 4; ++m)
        #pragma unroll
        for (int r = 0; r < 4; ++r)
            labr[m * 4 + r] = labels[rowq + m * 16 + r];
    int labc[4];
    #pragma unroll
    for (int n = 0; n < 4; ++n) labc[n] = labels[col0 + n * 16];

    f32x4 acc[4][4];
    #pragma unroll
    for (int m = 0; m < 4; ++m)
        #pragma unroll
        for (int n = 0; n < 4; ++n)
            acc[m][n] = (f32x4){0.f, 0.f, 0.f, 0.f};

    // --- staging: linear LDS dest (global_load_lds), source chunk XOR-swizzled
    // so that swizzled ds_reads are 2-way-conflict max (rule 21: both sides).
    #define STAGE(buf, kt)                                                         \
    {                                                                              \
        const int kbase = (kt) * BK;                                               \
        _Pragma("unroll")                                                          \
        for (int i = 0; i < 4; ++i) {                                              \
            const int c    = i * 256 + tid;                                        \
            const int rowc = c >> 3;                                               \
            const int kcs  = (c & 7) ^ (rowc & 7);                                 \
            const unsigned short* gA = A + (size_t)(rbase + rowc) * DIM + kbase + kcs * 8; \
            const unsigned short* gB = A + (size_t)(cbase + rowc) * DIM + kbase + kcs * 8; \
            const int ldsOff = i * 4096 + wid * 1024;   /* bytes; +lane*16 by HW */\
            __builtin_amdgcn_global_load_lds(                                      \
                (const __attribute__((address_space(1))) void*)gA,                 \
                (__attribute__((address_space(3))) void*)((char*)As[buf] + ldsOff),\
                16, 0, 0);                                                         \
            __builtin_amdgcn_global_load_lds(                                      \
                (const __attribute__((address_space(1))) void*)gB,                 \
                (__attribute__((address_space(3))) void*)((char*)Bs[buf] + ldsOff),\
                16, 0, 0);                                                         \
        }                                                                          \
    }

    STAGE(0, 0);
    __syncthreads();          // vmcnt(0) drain of prologue + barrier

    int cur = 0;
    for (int kt = 0; kt < DIM / BK; ++kt) {
        if (kt < DIM / BK - 1) STAGE(cur ^ 1, kt + 1);   // prefetch next tile

        #pragma unroll
        for (int ks = 0; ks < 2; ++ks) {
            const int kd0 = ks * 4 + (lane >> 4);        // 16B data-chunk index
            bf16x8 af[4], bfr[4];
            #pragma unroll
            for (int m = 0; m < 4; ++m) {
                const int rowa = wr * 64 + m * 16 + (lane & 15);
                af[m] = *(const bf16x8*)&As[cur][rowa * BK + ((kd0 ^ (rowa & 7)) << 3)];
            }
            #pragma unroll
            for (int n = 0; n < 4; ++n) {
                const int rowb = wc * 64 + n * 16 + (lane & 15);
                bfr[n] = *(const bf16x8*)&Bs[cur][rowb * BK + ((kd0 ^ (rowb & 7)) << 3)];
            }
            #pragma unroll
            for (int m = 0; m < 4; ++m)
                #pragma unroll
                for (int n = 0; n < 4; ++n)
                    acc[m][n] = __builtin_amdgcn_mfma_f32_16x16x32_bf16(
                        af[m], bfr[n], acc[m][n], 0, 0, 0);
        }
        __syncthreads();      // waits lgkmcnt(0) (reads done) + vmcnt(0) (prefetch landed)
        cur ^= 1;
    }

    // ---------------- epilogue ----------------
    float sum_p[16], pos_p[16], cnt_p[16];
    #pragma unroll
    for (int i = 0; i < 16; ++i) { sum_p[i] = 0.f; pos_p[i] = 0.f; cnt_p[i] = 0.f; }
    float csum[4], cpos[4], ccnt[4];
    #pragma unroll
    for (int n = 0; n < 4; ++n) { csum[n] = 0.f; cpos[n] = 0.f; ccnt[n] = 0.f; }

    if (isDiag) {
        #pragma unroll
        for (int m = 0; m < 4; ++m)
            #pragma unroll
            for (int n = 0; n < 4; ++n) {
                const int gcol = col0 + n * 16;
                #pragma unroll
                for (int r = 0; r < 4; ++r) {
                    const float s    = acc[m][n][r] * INV_T;
                    const int   i16  = m * 4 + r;
                    const int   grow = rowq + m * 16 + r;
                    const bool  diag = (grow == gcol);
                    sum_p[i16] += diag ? 0.f : __expf(s);
                    if ((labr[i16] == labc[n]) && !diag) {
                        pos_p[i16] += s; cnt_p[i16] += 1.f;
                    }
                }
            }
    } else {
        #pragma unroll
        for (int m = 0; m < 4; ++m)
            #pragma unroll
            for (int n = 0; n < 4; ++n) {
                #pragma unroll
                for (int r = 0; r < 4; ++r) {
                    const float s   = acc[m][n][r] * INV_T;
                    const int   i16 = m * 4 + r;
                    const float e   = __expf(s);
                    sum_p[i16] += e;
                    csum[n]    += e;
                    if (labr[i16] == labc[n]) {
                        pos_p[i16] += s; cnt_p[i16] += 1.f;
                        cpos[n]    += s; ccnt[n]    += 1.f;
                    }
                }
            }
    }

    // row-side: reduce across the 16 lanes sharing each row, then atomics
    #pragma unroll
    for (int i = 0; i < 16; ++i) {
        float se = sum_p[i], pp = pos_p[i], cc = cnt_p[i];
        #pragma unroll
        for (int off = 1; off < 16; off <<= 1) {
            se += __shfl_xor(se, off, 16);
            pp += __shfl_xor(pp, off, 16);
            cc += __shfl_xor(cc, off, 16);
        }
        if ((lane & 15) == 0) {
            const int row = rowq + (i >> 2) * 16 + (i & 3);
            atomicAdd(&gsum[row], se);
            atomicAdd(&gpos[row], pp);
            atomicAdd(&gcnt[row], cc);
        }
    }

    // col-side (off-diagonal tiles only): reduce across the 4 lane-groups
    if (!isDiag) {
        #pragma unroll
        for (int n = 0; n < 4; ++n) {
            float se = csum[n], pp = cpos[n], cc = ccnt[n];
            se += __shfl_xor(se, 16, 64); se += __shfl_xor(se, 32, 64);
            pp += __shfl_xor(pp, 16, 64); pp += __shfl_xor(pp, 32, 64);
            cc += __shfl_xor(cc, 16, 64); cc += __shfl_xor(cc, 32, 64);
            if (lane < 16) {
                const int gcol = col0 + n * 16;
                atomicAdd(&gsum[gcol], se);
                atomicAdd(&gpos[gcol], pp);
                atomicAdd(&gcnt[gcol], cc);
            }
        }
    }
}

// ---------------- kernel 3: finalize ----------------
__global__ __launch_bounds__(1024) void finalize_kernel(
    const float* __restrict__ gsum, const float* __restrict__ gpos,
    const float* __restrict__ gcnt, float* __restrict__ out)
{
    const int tid = threadIdx.x;
    float acc = 0.f;
    for (int r = tid; r < N_ROWS; r += 1024) {
        const float c = gcnt[r];
        if (c > 0.f) acc += logf(gsum[r]) - gpos[r] / c;
    }
    #pragma unroll
    for (int off = 32; off > 0; off >>= 1) acc += __shfl_down(acc, off, 64);
    __shared__ float ws[16];
    const int lane = tid & 63, wid = tid >> 6;
    if (lane == 0) ws[wid] = acc;
    __syncthreads();
    if (tid == 0) {
        float t = 0.f;
        #pragma unroll
        for (int i = 0; i < 16; ++i) t += ws[i];
        out[0] = t;
    }
}

extern "C" void kernel_launch(void* const* d_in, const int* in_sizes, int n_in,
                              void* d_out, int out_size, void* d_ws, size_t ws_size,
                              hipStream_t stream) {
    const float* V      = (const float*)d_in[0];
    const int*   labels = (const int*)d_in[1];
    float*       out    = (float*)d_out;

    unsigned short* Abf = (unsigned short*)d_ws;                      // 16 MB
    float* gsum = (float*)((char*)d_ws + (size_t)N_ROWS * DIM * 2);
    float* gpos = gsum + N_ROWS;
    float* gcnt = gpos + N_ROWS;

    hipMemsetAsync(gsum, 0, 3 * N_ROWS * sizeof(float), stream);
    norm_kernel<<<N_ROWS, 256, 0, stream>>>(V, Abf);
    dim3 grid(N_ROWS / BM, N_ROWS / BM);
    sim_kernel<<<grid, 256, 0, stream>>>(Abf, labels, gsum, gpos, gcnt);
    finalize_kernel<<<1, 1024, 0, stream>>>(gsum, gpos, gcnt, out);
}

// Round 3
// 129.826 us; speedup vs baseline: 2.7617x; 2.4176x over previous
//
#include <hip/hip_runtime.h>
#include <hip/hip_bf16.h>
#include <stdint.h>

#define N_ROWS 8192
#define DIM    1024
#define INV_T  14.2857142857142857f   // 1/0.07

#define BM 128
#define BK 64
#define NTILE  (N_ROWS / BM)     // 64 tiles per dim
#define NSLICE (2 * NTILE)       // 128 column-slices of 64 cols each

typedef __bf16 bf16x8 __attribute__((ext_vector_type(8)));
typedef float  f32x4  __attribute__((ext_vector_type(4)));

__device__ __forceinline__ unsigned short f2bf(float x) {
    __hip_bfloat16 h = __float2bfloat16(x);
    return *reinterpret_cast<unsigned short*>(&h);
}

// ---------------- kernel 1: row-normalize f32 -> bf16 ----------------
__global__ __launch_bounds__(256) void norm_kernel(
    const float* __restrict__ V, unsigned short* __restrict__ A)
{
    const int row  = blockIdx.x;
    const int tid  = threadIdx.x;
    const int lane = tid & 63, wid = tid >> 6;

    const float4* vp = (const float4*)(V + (size_t)row * DIM);
    float4 v = vp[tid];
    float ss = v.x*v.x + v.y*v.y + v.z*v.z + v.w*v.w;
    #pragma unroll
    for (int off = 32; off > 0; off >>= 1) ss += __shfl_down(ss, off, 64);

    __shared__ float wsum[4];
    if (lane == 0) wsum[wid] = ss;
    __syncthreads();
    const float inv = 1.0f / sqrtf(wsum[0] + wsum[1] + wsum[2] + wsum[3]);

    ushort4 o;
    o.x = f2bf(v.x * inv);
    o.y = f2bf(v.y * inv);
    o.z = f2bf(v.z * inv);
    o.w = f2bf(v.w * inv);
    *(ushort4*)(A + (size_t)row * DIM + tid * 4) = o;
}

// ---------------- kernel 2: fused symmetric sim GEMM + epilogue ----------------
// grid (64, 33): block handles unordered tile pair {rt, ct=(rt+ctl)&63}.
// ctl==0 -> diagonal tile (full square, row-side only).
// ctl==32 valid only for rt<32 (else the pair would be generated twice).
// Partials: partial[row][slice], slice = tile*2 + half (64 cols each).
// Each (row, slice) entry is written by EXACTLY ONE wave -> plain stores, no atomics.
__global__ __launch_bounds__(256, 3) void sim_kernel(
    const unsigned short* __restrict__ A, const int* __restrict__ labels,
    float* __restrict__ psum, float* __restrict__ ppos, float* __restrict__ pcnt)
{
    __shared__ __align__(16) unsigned short As[BM * BK];
    __shared__ __align__(16) unsigned short Bs[BM * BK];

    const int rt  = blockIdx.x;
    const int ctl = blockIdx.y;
    if (ctl == NTILE / 2 && rt >= NTILE / 2) return;
    const int  ct     = (rt + ctl) & (NTILE - 1);
    const bool isDiag = (ctl == 0);

    const int tid  = threadIdx.x;
    const int lane = tid & 63;
    const int wid  = tid >> 6;
    const int wr   = wid >> 1;      // wave row 0..1
    const int wc   = wid & 1;       // wave col 0..1

    const int rbase = rt * BM;
    const int cbase = ct * BM;

    const int rowq = rbase + wr * 64 + ((lane >> 4) << 2);
    const int col0 = cbase + wc * 64 + (lane & 15);

    int labr[16];
    #pragma unroll
    for (int m = 0; m < 4; ++m)
        #pragma unroll
        for (int r = 0; r < 4; ++r)
            labr[m * 4 + r] = labels[rowq + m * 16 + r];
    int labc[4];
    #pragma unroll
    for (int n = 0; n < 4; ++n) labc[n] = labels[col0 + n * 16];

    f32x4 acc[4][4];
    #pragma unroll
    for (int m = 0; m < 4; ++m)
        #pragma unroll
        for (int n = 0; n < 4; ++n)
            acc[m][n] = (f32x4){0.f, 0.f, 0.f, 0.f};

    // single-buffer m97-style staging; source-chunk XOR swizzle (rule 21 pair
    // with the swizzled ds_read below)
    #define STAGE(kt)                                                              \
    {                                                                              \
        const int kbase = (kt) * BK;                                               \
        _Pragma("unroll")                                                          \
        for (int i = 0; i < 4; ++i) {                                              \
            const int c    = i * 256 + tid;                                        \
            const int rowc = c >> 3;                                               \
            const int kcs  = (c & 7) ^ (rowc & 7);                                 \
            const unsigned short* gA = A + (size_t)(rbase + rowc) * DIM + kbase + kcs * 8; \
            const unsigned short* gB = A + (size_t)(cbase + rowc) * DIM + kbase + kcs * 8; \
            const int ldsOff = i * 4096 + wid * 1024;   /* +lane*16 by HW */       \
            __builtin_amdgcn_global_load_lds(                                      \
                (const __attribute__((address_space(1))) void*)gA,                 \
                (__attribute__((address_space(3))) void*)((char*)As + ldsOff),     \
                16, 0, 0);                                                         \
            __builtin_amdgcn_global_load_lds(                                      \
                (const __attribute__((address_space(1))) void*)gB,                 \
                (__attribute__((address_space(3))) void*)((char*)Bs + ldsOff),     \
                16, 0, 0);                                                         \
        }                                                                          \
    }

    for (int kt = 0; kt < DIM / BK; ++kt) {
        STAGE(kt);
        __syncthreads();      // drains vmcnt(0): tiles resident

        #pragma unroll
        for (int ks = 0; ks < 2; ++ks) {
            const int kd0 = ks * 4 + (lane >> 4);        // 16B chunk index
            bf16x8 af[4], bfr[4];
            #pragma unroll
            for (int m = 0; m < 4; ++m) {
                const int rowa = wr * 64 + m * 16 + (lane & 15);
                af[m] = *(const bf16x8*)&As[rowa * BK + ((kd0 ^ (rowa & 7)) << 3)];
            }
            #pragma unroll
            for (int n = 0; n < 4; ++n) {
                const int rowb = wc * 64 + n * 16 + (lane & 15);
                bfr[n] = *(const bf16x8*)&Bs[rowb * BK + ((kd0 ^ (rowb & 7)) << 3)];
            }
            #pragma unroll
            for (int m = 0; m < 4; ++m)
                #pragma unroll
                for (int n = 0; n < 4; ++n)
                    acc[m][n] = __builtin_amdgcn_mfma_f32_16x16x32_bf16(
                        af[m], bfr[n], acc[m][n], 0, 0, 0);
        }
        __syncthreads();      // reads done before next overwrite
    }

    // ---------------- epilogue ----------------
    float sum_p[16], pos_p[16], cnt_p[16];
    #pragma unroll
    for (int i = 0; i < 16; ++i) { sum_p[i] = 0.f; pos_p[i] = 0.f; cnt_p[i] = 0.f; }
    float csum[4], cpos[4], ccnt[4];
    #pragma unroll
    for (int n = 0; n < 4; ++n) { csum[n] = 0.f; cpos[n] = 0.f; ccnt[n] = 0.f; }

    if (isDiag) {
        #pragma unroll
        for (int m = 0; m < 4; ++m)
            #pragma unroll
            for (int n = 0; n < 4; ++n) {
                const int gcol = col0 + n * 16;
                #pragma unroll
                for (int r = 0; r < 4; ++r) {
                    const float s    = acc[m][n][r] * INV_T;
                    const int   i16  = m * 4 + r;
                    const int   grow = rowq + m * 16 + r;
                    const bool  diag = (grow == gcol);
                    sum_p[i16] += diag ? 0.f : __expf(s);
                    if ((labr[i16] == labc[n]) && !diag) {
                        pos_p[i16] += s; cnt_p[i16] += 1.f;
                    }
                }
            }
    } else {
        #pragma unroll
        for (int m = 0; m < 4; ++m)
            #pragma unroll
            for (int n = 0; n < 4; ++n) {
                #pragma unroll
                for (int r = 0; r < 4; ++r) {
                    const float s   = acc[m][n][r] * INV_T;
                    const int   i16 = m * 4 + r;
                    const float e   = __expf(s);
                    sum_p[i16] += e;
                    csum[n]    += e;
                    if (labr[i16] == labc[n]) {
                        pos_p[i16] += s; cnt_p[i16] += 1.f;
                        cpos[n]    += s; ccnt[n]    += 1.f;
                    }
                }
            }
    }

    // row-side: reduce across the 16 lanes sharing each row -> slice ct*2+wc
    #pragma unroll
    for (int i = 0; i < 16; ++i) {
        float se = sum_p[i], pp = pos_p[i], cc = cnt_p[i];
        #pragma unroll
        for (int off = 1; off < 16; off <<= 1) {
            se += __shfl_xor(se, off, 16);
            pp += __shfl_xor(pp, off, 16);
            cc += __shfl_xor(cc, off, 16);
        }
        if ((lane & 15) == 0) {
            const int row = rowq + (i >> 2) * 16 + (i & 3);
            const size_t idx = (size_t)row * NSLICE + ct * 2 + wc;
            psum[idx] = se;
            ppos[idx] = pp;
            pcnt[idx] = cc;
        }
    }

    // col-side (off-diag only): reduce across 4 lane-groups -> slice rt*2+wr
    if (!isDiag) {
        #pragma unroll
        for (int n = 0; n < 4; ++n) {
            float se = csum[n], pp = cpos[n], cc = ccnt[n];
            se += __shfl_xor(se, 16, 64); se += __shfl_xor(se, 32, 64);
            pp += __shfl_xor(pp, 16, 64); pp += __shfl_xor(pp, 32, 64);
            cc += __shfl_xor(cc, 16, 64); cc += __shfl_xor(cc, 32, 64);
            if (lane < 16) {
                const int gcol = col0 + n * 16;
                const size_t idx = (size_t)gcol * NSLICE + rt * 2 + wr;
                psum[idx] = se;
                ppos[idx] = pp;
                pcnt[idx] = cc;
            }
        }
    }
}

// ---------------- kernel 3a: per-row reduce over 128 slices ----------------
__global__ __launch_bounds__(128) void finalize1_kernel(
    const float* __restrict__ psum, const float* __restrict__ ppos,
    const float* __restrict__ pcnt, float* __restrict__ bpart)
{
    const int row  = blockIdx.x * 128 + threadIdx.x;
    const int lane = threadIdx.x & 63, wid = threadIdx.x >> 6;

    const float4* vs = (const float4*)(psum + (size_t)row * NSLICE);
    const float4* vp = (const float4*)(ppos + (size_t)row * NSLICE);
    const float4* vc = (const float4*)(pcnt + (size_t)row * NSLICE);
    float s = 0.f, p = 0.f, c = 0.f;
    #pragma unroll
    for (int i = 0; i < NSLICE / 4; ++i) {
        float4 a = vs[i]; s += a.x + a.y + a.z + a.w;
        float4 b = vp[i]; p += b.x + b.y + b.z + b.w;
        float4 d = vc[i]; c += d.x + d.y + d.z + d.w;
    }
    float per = (c > 0.f) ? (logf(s) - p / c) : 0.f;
    #pragma unroll
    for (int off = 32; off > 0; off >>= 1) per += __shfl_down(per, off, 64);
    __shared__ float w2[2];
    if (lane == 0) w2[wid] = per;
    __syncthreads();
    if (threadIdx.x == 0) bpart[blockIdx.x] = w2[0] + w2[1];
}

// ---------------- kernel 3b: final 64-way sum ----------------
__global__ __launch_bounds__(64) void finalize2_kernel(
    const float* __restrict__ bpart, float* __restrict__ out)
{
    const int lane = threadIdx.x;
    float v = bpart[lane];
    #pragma unroll
    for (int off = 32; off > 0; off >>= 1) v += __shfl_down(v, off, 64);
    if (lane == 0) out[0] = v;
}

extern "C" void kernel_launch(void* const* d_in, const int* in_sizes, int n_in,
                              void* d_out, int out_size, void* d_ws, size_t ws_size,
                              hipStream_t stream) {
    const float* V      = (const float*)d_in[0];
    const int*   labels = (const int*)d_in[1];
    float*       out    = (float*)d_out;

    // ws layout: Abf 16 MB | psum 4 MB | ppos 4 MB | pcnt 4 MB | bpart 256 B
    unsigned short* Abf = (unsigned short*)d_ws;
    char* base = (char*)d_ws + (size_t)N_ROWS * DIM * 2;
    float* psum  = (float*)(base);
    float* ppos  = (float*)(base + (size_t)N_ROWS * NSLICE * 4);
    float* pcnt  = (float*)(base + (size_t)N_ROWS * NSLICE * 8);
    float* bpart = (float*)(base + (size_t)N_ROWS * NSLICE * 12);

    norm_kernel<<<N_ROWS, 256, 0, stream>>>(V, Abf);
    dim3 grid(NTILE, NTILE / 2 + 1);   // (64, 33)
    sim_kernel<<<grid, 256, 0, stream>>>(Abf, labels, psum, ppos, pcnt);
    finalize1_kernel<<<N_ROWS / 128, 128, 0, stream>>>(psum, ppos, pcnt, bpart);
    finalize2_kernel<<<1, 64, 0, stream>>>(bpart, out);
}